// Round 2
// baseline (783.234 us; speedup 1.0000x reference)
//
#include <hip/hip_runtime.h>

// ---------------------------------------------------------------------------
// KeyValueMemoryRecallNet, R4: barrier-free independent waves.
//   - 128 blocks x 256 threads (4 waves). Wave w owns batch rows {4*q4 + w}.
//   - R3's cross-wave h relay + s_barrier is REMOVED. Each wave writes its
//     own 4 rows of h into a PRIVATE double-buffered LDS tile and reads the
//     A-fragment back (rotated read). MFMA row-independence means the 12
//     unwritten rows (zero) only pollute unused C components (r != 0).
//   - Relay is bank-swizzled: chunk ^= (row>>1)&3  -> 2-way conflicts (free)
//     on the ds_read_b128 (was 8-way in R3).
//   - No s_barrier / no inline-asm waitcnt: compiler tracks the same-wave
//     ds_write -> ds_read dependency and emits lgkmcnt itself.
//   - MFMA issue placed right after the relay read; attention + global
//     stores afterwards so their VALU overlaps ds/MFMA latency.
//
// MFMA 16x16x32 bf16 layouts (validated in R1):
//   A-frag: lane l holds A[row = l%16][k = 8*(l/16)+j]
//   B-frag: lane l holds B[k = 8*(l/16)+j][col = l%16]
//   C/D   : lane l holds D[row = 4*(l/16)+r][col = l%16]
// Rotated A-frag (read row (c+w)&15): D'[4*q4+r] = D[(4*q4+r+w)&15], so
// r=0 gives row 4*q4+w exactly (4*q4+w <= 15, no wrap).
// ---------------------------------------------------------------------------

typedef __attribute__((ext_vector_type(4))) float f32x4;
typedef __attribute__((ext_vector_type(8))) __bf16 bf16x8;

#define NB 2048
#define SL 512
#define NIN 64
#define NH 32
#define NO 16

__device__ __forceinline__ float rcpf_(float x) { return __builtin_amdgcn_rcpf(x); }
__device__ __forceinline__ float sigmoidf_(float x) {
  return rcpf_(1.0f + __expf(-x));
}
__device__ __forceinline__ float tanhf_(float x) {
  return 1.0f - 2.0f * rcpf_(__expf(2.0f * x) + 1.0f);
}
__device__ __forceinline__ f32x4 splat4(float v) {
  f32x4 r; r[0] = v; r[1] = v; r[2] = v; r[3] = v; return r;
}

// DPP rotate-add reduction within each 16-lane row (groups == same l>>4).
template <int CTRL>
__device__ __forceinline__ float dpp_add_(float v) {
  int p = __builtin_amdgcn_update_dpp(0, __float_as_int(v), CTRL, 0xF, 0xF, true);
  return v + __int_as_float(p);
}
__device__ __forceinline__ float rowsum16(float v) {
  v = dpp_add_<0x121>(v);  // row_ror:1
  v = dpp_add_<0x122>(v);  // row_ror:2
  v = dpp_add_<0x124>(v);  // row_ror:4
  v = dpp_add_<0x128>(v);  // row_ror:8
  return v;
}

// uniform-w component picks (3 cndmask; used only one-time / in prologue)
__device__ __forceinline__ float pick4v(f32x4 v, int w) {
  float a = (w & 2) ? v[2] : v[0];
  float b = (w & 2) ? v[3] : v[1];
  return (w & 1) ? b : a;
}
__device__ __forceinline__ float pick4f(float a0, float a1, float a2, float a3, int w) {
  float a = (w & 2) ? a2 : a0;
  float b = (w & 2) ? a3 : a1;
  return (w & 1) ? b : a;
}

// B-frag of W^T (for y = x @ W^T): B[k][col] = W[col][k]. W row-major [out][in].
__device__ __forceinline__ bf16x8 ldfrag(const float* __restrict__ W, int indim,
                                         int row, int k0) {
  bf16x8 r;
#pragma unroll
  for (int j = 0; j < 8; ++j) {
    int k = k0 + j;
    float w = (k < indim) ? W[row * indim + k] : 0.0f;
    r[j] = (__bf16)w;
  }
  return r;
}
// B-frag of W (for y = x @ W): B[k][col] = W[k][col]. W row-major [K][ncol].
__device__ __forceinline__ bf16x8 ldfragT(const float* __restrict__ W, int ncol,
                                          int col, int k0) {
  bf16x8 r;
#pragma unroll
  for (int j = 0; j < 8; ++j) r[j] = (__bf16)W[(k0 + j) * ncol + col];
  return r;
}

#define MFMA(A, B, C) __builtin_amdgcn_mfma_f32_16x16x32_bf16((A), (B), (C), 0, 0, 0)

__global__ __launch_bounds__(256, 1)
void kvmr_kernel(const float* __restrict__ inputs,   // [2048][512][64]
                 const float* __restrict__ w_ih,     // [96][66]
                 const float* __restrict__ w_hh,     // [96][32]
                 const float* __restrict__ b_ih,     // [96]
                 const float* __restrict__ b_hh,     // [96]
                 const float* __restrict__ W_key,    // [64][32]
                 const float* __restrict__ b_key,    // [64]
                 const float* __restrict__ W_query,  // [64][32]
                 const float* __restrict__ b_query,  // [64]
                 const float* __restrict__ W_value,  // [64][32]
                 const float* __restrict__ b_value,  // [64]
                 const float* __restrict__ W_recall, // [2][64]
                 const float* __restrict__ b_recall, // [2]
                 const float* __restrict__ W_out,    // [16][32]
                 const float* __restrict__ b_out,    // [16]
                 float* __restrict__ out_all) {      // outputs | hiddens
  const int tid = threadIdx.x;
  const int l  = tid & 63;
  const int c  = l & 15;
  const int q4 = l >> 4;
  const int w  = tid >> 6;       // wave id == owned r index
  const int b0 = blockIdx.x * 16;

  __shared__ __align__(16) __bf16 h_pro[4][16 * 32];       // per-wave prologue relay
  __shared__ __align__(16) __bf16 kv_pro[4][3][16 * 64];   // per-wave fold relay
  __shared__ __align__(16) __bf16 relay[4][2][16 * 32];    // per-wave PRIVATE h relay

  // zero the private relay (unwritten rows must be benign for MFMA)
  {
    uint32_t* z = (uint32_t*)&relay[w][0][0];  // 2 bufs * 512 bf16 = 256 u32... (1KB=512u32/wave pair)
#pragma unroll
    for (int i = 0; i < 8; ++i) z[l + 64 * i] = 0u;
  }

  // ---- weights as register-resident B-fragments ----
  bf16x8 Bih[6][2];  // gate tiles r0 r1 z0 z1 n0 n1; k-chunks x[0:32), x[32:64)
  bf16x8 Bhh[6];
#pragma unroll
  for (int g = 0; g < 6; ++g) {
#pragma unroll
    for (int kc = 0; kc < 2; ++kc)
      Bih[g][kc] = ldfrag(w_ih, 66, 16 * g + c, 32 * kc + 8 * q4);
    Bhh[g] = ldfrag(w_hh, 32, 16 * g + c, 8 * q4);
  }
  bf16x8 Bq[4], Bk[4], Bv[4];
#pragma unroll
  for (int g = 0; g < 4; ++g) {
    Bq[g] = ldfrag(W_query, 32, 16 * g + c, 8 * q4);
    Bk[g] = ldfrag(W_key,   32, 16 * g + c, 8 * q4);
    Bv[g] = ldfrag(W_value, 32, 16 * g + c, 8 * q4);
  }
  bf16x8 Bo = ldfrag(W_out, 32, c, 8 * q4);

  // retr rank-2 update coefficients: w_ih[:, 64] and w_ih[:, 65], col = 16g+c
  float wih64[6], wih65[6];
#pragma unroll
  for (int g = 0; g < 6; ++g) {
    wih64[g] = w_ih[(16 * g + c) * 66 + 64];
    wih65[g] = w_ih[(16 * g + c) * 66 + 65];
  }
  float wr0f[4], wr1f[4];
#pragma unroll
  for (int g = 0; g < 4; ++g) {
    wr0f[g] = W_recall[16 * g + c];
    wr1f[g] = W_recall[64 + 16 * g + c];
  }

  float bias_rz[4], bias_xn[2], bias_hn[2];
#pragma unroll
  for (int g = 0; g < 4; ++g) bias_rz[g] = b_ih[16 * g + c] + b_hh[16 * g + c];
#pragma unroll
  for (int gg = 0; gg < 2; ++gg) {
    bias_xn[gg] = b_ih[64 + 16 * gg + c];
    bias_hn[gg] = b_hh[64 + 16 * gg + c];
  }
  float bq4[4], bk4[4], bv4[4];
#pragma unroll
  for (int g = 0; g < 4; ++g) {
    bq4[g] = b_query[16 * g + c];
    bk4[g] = b_key[16 * g + c];
    bv4[g] = b_value[16 * g + c];
  }
  float bo1 = b_out[c];
  float br0 = b_recall[0], br1 = b_recall[1];

  // sliced global store bases: row b0 + 4*q4 + w, col c
  float* outW = out_all + (size_t)(b0 + 4 * q4 + w) * SL * NO + c;
  float* hidW = out_all + (size_t)NB * SL * NO + (size_t)(b0 + 4 * q4 + w) * SL * NH + c;

  // ---- prologue state ----
  f32x4 hD0 = splat4(0.0f), hD1 = splat4(0.0f);
  f32x4 keysR[3][4], valsR[3][4];
#pragma unroll
  for (int s = 0; s < 3; ++s)
#pragma unroll
    for (int g = 0; g < 4; ++g) { keysR[s][g] = splat4(0.0f); valsR[s][g] = splat4(0.0f); }

  f32x4 hPartRZ[4], hPartHN[2];
#pragma unroll
  for (int g = 0; g < 4; ++g) hPartRZ[g] = splat4(bias_rz[g]);
#pragma unroll
  for (int gg = 0; gg < 2; ++gg) hPartHN[gg] = splat4(bias_hn[gg]);
  float retr0c[4] = {0.f, 0.f, 0.f, 0.f};
  float retr1c[4] = {0.f, 0.f, 0.f, 0.f};

  // ---- x double prefetch (unrotated; prologue computes all 16 rows) ----
  const float* xp = inputs + (size_t)(b0 + c) * (SL * NIN) + 8 * q4;
  f32x4 xb[2][4];
#pragma unroll
  for (int p = 0; p < 2; ++p) {
    const float* xq = xp + p * NIN;
    xb[p][0] = *(const f32x4*)(xq + 0);
    xb[p][1] = *(const f32x4*)(xq + 4);
    xb[p][2] = *(const f32x4*)(xq + 32);
    xb[p][3] = *(const f32x4*)(xq + 36);
  }

  __bf16* hp = &h_pro[w][0];

  // =========================================================================
  // Prologue: t = 0,1,2 (memory writes active) — redundant per wave,
  // private LDS, no sync; only the wave's own row slice stored globally.
  // =========================================================================
#pragma unroll
  for (int t = 0; t < 3; ++t) {
    const int pb = t & 1;
    bf16x8 ax0, ax1;
#pragma unroll
    for (int j = 0; j < 4; ++j) {
      ax0[j]     = (__bf16)xb[pb][0][j];
      ax0[4 + j] = (__bf16)xb[pb][1][j];
      ax1[j]     = (__bf16)xb[pb][2][j];
      ax1[4 + j] = (__bf16)xb[pb][3][j];
    }
    {
      const float* xq = xp + (t + 2) * NIN;
      xb[pb][0] = *(const f32x4*)(xq + 0);
      xb[pb][1] = *(const f32x4*)(xq + 4);
      xb[pb][2] = *(const f32x4*)(xq + 32);
      xb[pb][3] = *(const f32x4*)(xq + 36);
    }

    f32x4 accRZ[4], accXN[2];
#pragma unroll
    for (int g = 0; g < 4; ++g) {
      f32x4 a = hPartRZ[g];
#pragma unroll
      for (int r = 0; r < 4; ++r) a[r] += retr0c[r] * wih64[g] + retr1c[r] * wih65[g];
      a = MFMA(ax0, Bih[g][0], a);
      a = MFMA(ax1, Bih[g][1], a);
      accRZ[g] = a;
    }
#pragma unroll
    for (int gg = 0; gg < 2; ++gg) {
      f32x4 a = splat4(bias_xn[gg]);
#pragma unroll
      for (int r = 0; r < 4; ++r) a[r] += retr0c[r] * wih64[4 + gg] + retr1c[r] * wih65[4 + gg];
      a = MFMA(ax0, Bih[4 + gg][0], a);
      a = MFMA(ax1, Bih[4 + gg][1], a);
      accXN[gg] = a;
    }

    f32x4 hn0, hn1;
#pragma unroll
    for (int r = 0; r < 4; ++r) {
      float rg0 = sigmoidf_(accRZ[0][r]);
      float zg0 = sigmoidf_(accRZ[2][r]);
      float ng0 = tanhf_(accXN[0][r] + rg0 * hPartHN[0][r]);
      hn0[r] = (1.0f - zg0) * ng0 + zg0 * hD0[r];
      float rg1 = sigmoidf_(accRZ[1][r]);
      float zg1 = sigmoidf_(accRZ[3][r]);
      float ng1 = tanhf_(accXN[1][r] + rg1 * hPartHN[1][r]);
      hn1[r] = (1.0f - zg1) * ng1 + zg1 * hD1[r];
    }
    hD0 = hn0; hD1 = hn1;

    // sliced hidden stores (own row only)
    hidW[t * NH]      = pick4v(hn0, w);
    hidW[t * NH + 16] = pick4v(hn1, w);
#pragma unroll
    for (int r = 0; r < 4; ++r) {
      hp[(4 * q4 + r) * 32 + c]      = (__bf16)hn0[r];
      hp[(4 * q4 + r) * 32 + c + 16] = (__bf16)hn1[r];
    }
    bf16x8 hA = *(const bf16x8*)&hp[c * 32 + 8 * q4];

#pragma unroll
    for (int g = 0; g < 4; ++g) hPartRZ[g] = MFMA(hA, Bhh[g], splat4(bias_rz[g]));
#pragma unroll
    for (int gg = 0; gg < 2; ++gg) hPartHN[gg] = MFMA(hA, Bhh[4 + gg], splat4(bias_hn[gg]));
    f32x4 oT = MFMA(hA, Bo, splat4(bo1));
    outW[t * NO] = pick4v(oT, w);

    f32x4 qT[4], kT[4], vT[4];
#pragma unroll
    for (int g = 0; g < 4; ++g) {
      qT[g] = MFMA(hA, Bq[g], splat4(bq4[g]));
      kT[g] = MFMA(hA, Bk[g], splat4(bk4[g]));
      vT[g] = MFMA(hA, Bv[g], splat4(bv4[g]));
    }

    // attention over slots < t (scores on pre-write memory)
#pragma unroll
    for (int r = 0; r < 4; ++r) {
      float d0 = qT[0][r] * keysR[0][0][r] + qT[1][r] * keysR[0][1][r] +
                 qT[2][r] * keysR[0][2][r] + qT[3][r] * keysR[0][3][r];
      float d1 = qT[0][r] * keysR[1][0][r] + qT[1][r] * keysR[1][1][r] +
                 qT[2][r] * keysR[1][2][r] + qT[3][r] * keysR[1][3][r];
      float s0 = (t > 0) ? rowsum16(d0) : -1e30f;
      float s1 = (t > 1) ? rowsum16(d1) : -1e30f;
      float s2 = -1e30f;  // t<3 => slot2 never visible in prologue
      float mx = fmaxf(s0, fmaxf(s1, s2));
      float e0 = __expf(s0 - mx), e1 = __expf(s1 - mx), e2 = __expf(s2 - mx);
      float inv = rcpf_(e0 + e1 + e2);
      float u0 = 0.f, u1 = 0.f;
#pragma unroll
      for (int g = 0; g < 4; ++g) {
        float rd = (e0 * valsR[0][g][r] + e1 * valsR[1][g][r] + e2 * valsR[2][g][r]) * inv;
        u0 += rd * wr0f[g];
        u1 += rd * wr1f[g];
      }
      u0 = rowsum16(u0);
      u1 = rowsum16(u1);
      retr0c[r] = (t > 0) ? (u0 + br0) : 0.0f;
      retr1c[r] = (t > 0) ? (u1 + br1) : 0.0f;
    }

    // write slot t
#pragma unroll
    for (int g = 0; g < 4; ++g) { keysR[t][g] = kT[g]; valsR[t][g] = vT[g]; }
  }

  // =========================================================================
  // Fold (memory frozen after t=2):
  //   M[s]  = keys[s] @ W_query        (per-batch effective score weights)
  //   Cq[s] = b_query . keys[s]        (score constant)
  //   VR[s] = vals[s] . W_recall^T     (pre-reduced recall contributions)
  // =========================================================================
#pragma unroll
  for (int s = 0; s < 3; ++s)
#pragma unroll
    for (int g = 0; g < 4; ++g)
#pragma unroll
      for (int r = 0; r < 4; ++r)
        kv_pro[w][s][(4 * q4 + r) * 64 + 16 * g + c] = (__bf16)keysR[s][g][r];

  bf16x8 Bwq[2][2];  // [kchunk][coltile], B = W_query ([64][32] row-major)
#pragma unroll
  for (int ch = 0; ch < 2; ++ch)
#pragma unroll
    for (int ct = 0; ct < 2; ++ct)
      Bwq[ch][ct] = ldfragT(W_query, 32, 16 * ct + c, 32 * ch + 8 * q4);

  float M0c[3][4], M1c[3][4], Cq[3][4], VRa[3][4], VRb[3][4];
#pragma unroll
  for (int s = 0; s < 3; ++s) {
    const bf16x8 ak0 = *(const bf16x8*)&kv_pro[w][s][c * 64 + 8 * q4];
    const bf16x8 ak1 = *(const bf16x8*)&kv_pro[w][s][c * 64 + 32 + 8 * q4];
    f32x4 m0 = MFMA(ak1, Bwq[1][0], MFMA(ak0, Bwq[0][0], splat4(0.0f)));
    f32x4 m1 = MFMA(ak1, Bwq[1][1], MFMA(ak0, Bwq[0][1], splat4(0.0f)));
#pragma unroll
    for (int r = 0; r < 4; ++r) {
      M0c[s][r] = m0[r];
      M1c[s][r] = m1[r];
      Cq[s][r] = rowsum16(keysR[s][0][r] * bq4[0] + keysR[s][1][r] * bq4[1] +
                          keysR[s][2][r] * bq4[2] + keysR[s][3][r] * bq4[3]);
      VRa[s][r] = rowsum16(valsR[s][0][r] * wr0f[0] + valsR[s][1][r] * wr0f[1] +
                           valsR[s][2][r] * wr0f[2] + valsR[s][3][r] * wr0f[3]);
      VRb[s][r] = rowsum16(valsR[s][0][r] * wr1f[0] + valsR[s][1][r] * wr1f[1] +
                           valsR[s][2][r] * wr1f[2] + valsR[s][3][r] * wr1f[3]);
    }
  }

  // ---- W slices (one-time uniform cndmask extraction) ----
  float M0w[3], M1w[3], Cqw[3], VAw[3], VBw[3];
#pragma unroll
  for (int s = 0; s < 3; ++s) {
    M0w[s] = pick4f(M0c[s][0], M0c[s][1], M0c[s][2], M0c[s][3], w);
    M1w[s] = pick4f(M1c[s][0], M1c[s][1], M1c[s][2], M1c[s][3], w);
    Cqw[s] = pick4f(Cq[s][0],  Cq[s][1],  Cq[s][2],  Cq[s][3],  w);
    VAw[s] = pick4f(VRa[s][0], VRa[s][1], VRa[s][2], VRa[s][3], w);
    VBw[s] = pick4f(VRb[s][0], VRb[s][1], VRb[s][2], VRb[s][3], w);
  }

  // =========================================================================
  // t = 3 closed form: h_3 flushed to 0.
  //   hidden_3 = 0, out_3 = b_out, hPart_4 = biases, retr_4 = softmax(Cq).VR
  // =========================================================================
  hidW[3 * NH]      = 0.0f;
  hidW[3 * NH + 16] = 0.0f;
  outW[3 * NO]      = bo1;

  float retr0, retr1;
  {
    float s0 = Cqw[0], s1 = Cqw[1], s2 = Cqw[2];
    float mx = fmaxf(s0, fmaxf(s1, s2));
    float e0 = __expf(s0 - mx), e1 = __expf(s1 - mx), e2 = __expf(s2 - mx);
    float inv = rcpf_(e0 + e1 + e2);
    retr0 = br0 + (e0 * VAw[0] + e1 * VAw[1] + e2 * VAw[2]) * inv;
    retr1 = br1 + (e0 * VBw[0] + e1 * VBw[1] + e2 * VBw[2]) * inv;
  }

  f32x4 hPRZ[4], hPHN[2];
#pragma unroll
  for (int g = 0; g < 4; ++g) hPRZ[g] = splat4(bias_rz[g]);
#pragma unroll
  for (int gg = 0; gg < 2; ++gg) hPHN[gg] = splat4(bias_hn[gg]);
  float h0p = 0.0f, h1p = 0.0f;

  // rotated x pipeline: lane (q4,c) loads batch row b0 + (c+w)&15
  const float* xpr = inputs + (size_t)(b0 + ((c + w) & 15)) * (SL * NIN) + 8 * q4;
  f32x4 xbr[2][4];
#pragma unroll
  for (int p = 0; p < 2; ++p) {
    const float* xq = xpr + (4 + p) * NIN;
    xbr[p][0] = *(const f32x4*)(xq + 0);
    xbr[p][1] = *(const f32x4*)(xq + 4);
    xbr[p][2] = *(const f32x4*)(xq + 32);
    xbr[p][3] = *(const f32x4*)(xq + 36);
  }

  // xa_4 (x-part of gate pre-activations for t=4; row 4q4+w at component 0)
  f32x4 xa6[6];
  {
    bf16x8 ax0, ax1;
#pragma unroll
    for (int j = 0; j < 4; ++j) {
      ax0[j]     = (__bf16)xbr[0][0][j];
      ax0[4 + j] = (__bf16)xbr[0][1][j];
      ax1[j]     = (__bf16)xbr[0][2][j];
      ax1[4 + j] = (__bf16)xbr[0][3][j];
    }
#pragma unroll
    for (int g = 0; g < 4; ++g)
      xa6[g] = MFMA(ax1, Bih[g][1], MFMA(ax0, Bih[g][0], splat4(0.0f)));
#pragma unroll
    for (int gg = 0; gg < 2; ++gg)
      xa6[4 + gg] = MFMA(ax1, Bih[4 + gg][1], MFMA(ax0, Bih[4 + gg][0], splat4(bias_xn[gg])));
  }
  {  // refill slot 0 with x_6 (consumed at t=5)
    const float* xq = xpr + 6 * NIN;
    xbr[0][0] = *(const f32x4*)(xq + 0);
    xbr[0][1] = *(const f32x4*)(xq + 4);
    xbr[0][2] = *(const f32x4*)(xq + 32);
    xbr[0][3] = *(const f32x4*)(xq + 36);
  }

  // private-relay addressing (bank-swizzled: chunk ^= (row>>1)&3)
  const int Rrow = 4 * q4 + w;                  // row this lane writes
  const int swR  = (Rrow >> 1) & 3;
  const int wi0  = Rrow * 32 + ((((c >> 3) ^ swR) << 3) | (c & 7));          // h0 (col c)
  const int wi1  = Rrow * 32 + (((((c >> 3) + 2) ^ swR) << 3) | (c & 7));    // h1 (col c+16)
  const int lr   = (c + w) & 15;                // rotated read row
  const int ri   = lr * 32 + ((q4 ^ ((lr >> 1) & 3)) << 3);                  // A-frag read idx

  // =========================================================================
  // Steady state: t = 4..511. No barriers: wave-private relay only.
  // =========================================================================
#pragma unroll 2
  for (int t = 4; t < SL; ++t) {
    // ---- P1: gates + h update for own row (all scalar, static [0]) ----
    float pr0 = xa6[0][0] + hPRZ[0][0] + retr0 * wih64[0] + retr1 * wih65[0];
    float pr1 = xa6[1][0] + hPRZ[1][0] + retr0 * wih64[1] + retr1 * wih65[1];
    float pz0 = xa6[2][0] + hPRZ[2][0] + retr0 * wih64[2] + retr1 * wih65[2];
    float pz1 = xa6[3][0] + hPRZ[3][0] + retr0 * wih64[3] + retr1 * wih65[3];
    float pn0 = xa6[4][0] + retr0 * wih64[4] + retr1 * wih65[4];
    float pn1 = xa6[5][0] + retr0 * wih64[5] + retr1 * wih65[5];
    float rg0 = sigmoidf_(pr0), rg1 = sigmoidf_(pr1);
    float zg0 = sigmoidf_(pz0), zg1 = sigmoidf_(pz1);
    float ng0 = tanhf_(pn0 + rg0 * hPHN[0][0]);
    float ng1 = tanhf_(pn1 + rg1 * hPHN[1][0]);
    float h0 = (1.0f - zg0) * ng0 + zg0 * h0p;
    float h1 = (1.0f - zg1) * ng1 + zg1 * h1p;
    h0p = h0; h1p = h1;

    // private relay write (own row only; swizzled)
    {
      __bf16* rb = &relay[w][t & 1][0];
      rb[wi0] = (__bf16)h0;
      rb[wi1] = (__bf16)h1;
    }

    // ---- P2: MFMAs off the private rotated relay + x pipeline ----
    const bf16x8 hA = *(const bf16x8*)&relay[w][t & 1][ri];
#pragma unroll
    for (int g = 0; g < 4; ++g) hPRZ[g] = MFMA(hA, Bhh[g], splat4(bias_rz[g]));
#pragma unroll
    for (int gg = 0; gg < 2; ++gg) hPHN[gg] = MFMA(hA, Bhh[4 + gg], splat4(bias_hn[gg]));
    f32x4 oT = MFMA(hA, Bo, splat4(bo1));

    {  // xa_{t+1} from xbr[(t+1)&1]; then refill that slot with x_{t+3}
      const int sb = (t + 1) & 1;
      bf16x8 ax0, ax1;
#pragma unroll
      for (int j = 0; j < 4; ++j) {
        ax0[j]     = (__bf16)xbr[sb][0][j];
        ax0[4 + j] = (__bf16)xbr[sb][1][j];
        ax1[j]     = (__bf16)xbr[sb][2][j];
        ax1[4 + j] = (__bf16)xbr[sb][3][j];
      }
#pragma unroll
      for (int g = 0; g < 4; ++g)
        xa6[g] = MFMA(ax1, Bih[g][1], MFMA(ax0, Bih[g][0], splat4(0.0f)));
#pragma unroll
      for (int gg = 0; gg < 2; ++gg)
        xa6[4 + gg] = MFMA(ax1, Bih[4 + gg][1], MFMA(ax0, Bih[4 + gg][0], splat4(bias_xn[gg])));
      if (t + 3 < SL) {
        const float* xq = xpr + (t + 3) * NIN;
        xbr[sb][0] = *(const f32x4*)(xq + 0);
        xbr[sb][1] = *(const f32x4*)(xq + 4);
        xbr[sb][2] = *(const f32x4*)(xq + 32);
        xbr[sb][3] = *(const f32x4*)(xq + 36);
      }
    }

    // ---- attention + stores (overlap ds/MFMA latency) ----
    hidW[t * NH]      = h0;
    hidW[t * NH + 16] = h1;

    float p0 = h0 * M0w[0] + h1 * M1w[0];
    float p1 = h0 * M0w[1] + h1 * M1w[1];
    float p2 = h0 * M0w[2] + h1 * M1w[2];
    p0 = rowsum16(p0) + Cqw[0];
    p1 = rowsum16(p1) + Cqw[1];
    p2 = rowsum16(p2) + Cqw[2];
    float mx = fmaxf(p0, fmaxf(p1, p2));
    float e0 = __expf(p0 - mx), e1 = __expf(p1 - mx), e2 = __expf(p2 - mx);
    float inv = rcpf_(e0 + e1 + e2);
    retr0 = br0 + (e0 * VAw[0] + e1 * VAw[1] + e2 * VAw[2]) * inv;
    retr1 = br1 + (e0 * VBw[0] + e1 * VBw[1] + e2 * VBw[2]) * inv;

    outW[t * NO] = oT[0];
  }
}

extern "C" void kernel_launch(void* const* d_in, const int* in_sizes, int n_in,
                              void* d_out, int out_size, void* d_ws, size_t ws_size,
                              hipStream_t stream) {
  (void)in_sizes; (void)n_in; (void)out_size; (void)d_ws; (void)ws_size;
  const float* inputs   = (const float*)d_in[0];
  const float* w_ih     = (const float*)d_in[1];
  const float* w_hh     = (const float*)d_in[2];
  const float* b_ih     = (const float*)d_in[3];
  const float* b_hh     = (const float*)d_in[4];
  const float* W_key    = (const float*)d_in[5];
  const float* b_key    = (const float*)d_in[6];
  const float* W_query  = (const float*)d_in[7];
  const float* b_query  = (const float*)d_in[8];
  const float* W_value  = (const float*)d_in[9];
  const float* b_value  = (const float*)d_in[10];
  const float* W_recall = (const float*)d_in[11];
  const float* b_recall = (const float*)d_in[12];
  const float* W_out    = (const float*)d_in[13];
  const float* b_out    = (const float*)d_in[14];
  float* out = (float*)d_out;

  kvmr_kernel<<<dim3(128), dim3(256), 0, stream>>>(
      inputs, w_ih, w_hh, b_ih, b_hh, W_key, b_key, W_query, b_query,
      W_value, b_value, W_recall, b_recall, W_out, b_out, out);
}

// Round 6
// 602.720 us; speedup vs baseline: 1.2995x; 1.2995x over previous
//
#include <hip/hip_runtime.h>

// ---------------------------------------------------------------------------
// KeyValueMemoryRecallNet, R6 (2nd resubmit; two consecutive broker timeouts —
// this exact source has never reached hardware).
//   - 128 blocks x 256 threads (4 independent waves; wave w owns rows 4q4+w).
//   - h C->A transport via 4 pipelined ds_bpermute_b32 of packed bf16 pair
//     (sigma k-order trick, see notes below).
//   - 4-steps-per-MFMA xa packing. A row 4m+r carries x_{t+r}[row 4m+w],
//     so one 12-MFMA batch yields xa for 4 steps (D comp r = step t+r).
//     3 MFMA/step instead of 12; x loads 1/step instead of 4; no redundant
//     cross-wave input reads.
//   - Persistent MFMA C-quads (Zq / biasQ / bhnQ / boQ) — removes the
//     4x v_mov C-materialization per MFMA (~76 movs/step in R4).
//   - Global stores batched 16 steps deep (static slots).
//
// MFMA 16x16x32 bf16 layouts (validated in R1):
//   A-frag: lane l holds A[row = l%16][k-slot j]
//   B-frag: lane l holds B[k-slot j][col = l%16]
//   C/D   : lane l holds D[row = 4*(l/16)+r][col = l%16]
// sigma k-order (h path): slot j of lane (q4,c) <-> k = 4*q4 + (j>>1) + 16*(j&1).
// bpermute: dest lane (q4,c) pulls f_i from source lane 16*(c>>2)+4*q4+i, which
// holds pack(h[4*(c>>2)+w][4q4+i], h[...][4q4+i+16]) -> A[row c] = h[4*(c>>2)+w],
// D[4q4+r][c] = gh[own row 4q4+w][col c] for ALL r (comp 0 used).
// ---------------------------------------------------------------------------

typedef __attribute__((ext_vector_type(4))) float f32x4;
typedef __attribute__((ext_vector_type(8))) __bf16 bf16x8;

#define NB 2048
#define SL 512
#define NIN 64
#define NH 32
#define NO 16

__device__ __forceinline__ float rcpf_(float x) { return __builtin_amdgcn_rcpf(x); }
__device__ __forceinline__ float sigmoidf_(float x) {
  return rcpf_(1.0f + __expf(-x));
}
__device__ __forceinline__ float tanhf_(float x) {
  return 1.0f - 2.0f * rcpf_(__expf(2.0f * x) + 1.0f);
}
__device__ __forceinline__ f32x4 splat4(float v) {
  f32x4 r; r[0] = v; r[1] = v; r[2] = v; r[3] = v; return r;
}

// DPP rotate-add reduction within each 16-lane row (groups == same l>>4).
template <int CTRL>
__device__ __forceinline__ float dpp_add_(float v) {
  int p = __builtin_amdgcn_update_dpp(0, __float_as_int(v), CTRL, 0xF, 0xF, true);
  return v + __int_as_float(p);
}
__device__ __forceinline__ float rowsum16(float v) {
  v = dpp_add_<0x121>(v);  // row_ror:1
  v = dpp_add_<0x122>(v);  // row_ror:2
  v = dpp_add_<0x124>(v);  // row_ror:4
  v = dpp_add_<0x128>(v);  // row_ror:8
  return v;
}

__device__ __forceinline__ uint32_t cvtpk_(float lo, float hi) {
  uint32_t r;
  asm("v_cvt_pk_bf16_f32 %0, %1, %2" : "=v"(r) : "v"(lo), "v"(hi));
  return r;
}

__device__ __forceinline__ bf16x8 frag4(uint32_t a, uint32_t b, uint32_t c, uint32_t d) {
  union { uint32_t u[4]; bf16x8 v; } x;
  x.u[0] = a; x.u[1] = b; x.u[2] = c; x.u[3] = d;
  return x.v;
}

// uniform-w component picks (used only one-time / in prologue)
__device__ __forceinline__ float pick4v(f32x4 v, int w) {
  float a = (w & 2) ? v[2] : v[0];
  float b = (w & 2) ? v[3] : v[1];
  return (w & 1) ? b : a;
}
__device__ __forceinline__ float pick4f(float a0, float a1, float a2, float a3, int w) {
  float a = (w & 2) ? a2 : a0;
  float b = (w & 2) ? a3 : a1;
  return (w & 1) ? b : a;
}

// standard-order B-frag of W^T (y = x @ W^T): B[k][col] = W[col][k].
__device__ __forceinline__ bf16x8 ldfrag(const float* __restrict__ W, int indim,
                                         int row, int k0) {
  bf16x8 r;
#pragma unroll
  for (int j = 0; j < 8; ++j) {
    int k = k0 + j;
    float w = (k < indim) ? W[row * indim + k] : 0.0f;
    r[j] = (__bf16)w;
  }
  return r;
}
// sigma-order B-frag (indim==32): slot j -> k = 4*q4 + (j>>1) + ((j&1) ? 16 : 0)
__device__ __forceinline__ bf16x8 ldfragS(const float* __restrict__ W, int row, int q4) {
  bf16x8 r;
#pragma unroll
  for (int j = 0; j < 8; ++j) {
    int k = 4 * q4 + (j >> 1) + ((j & 1) ? 16 : 0);
    r[j] = (__bf16)W[row * 32 + k];
  }
  return r;
}
// B-frag of W (y = x @ W): B[k][col] = W[k][col].
__device__ __forceinline__ bf16x8 ldfragT(const float* __restrict__ W, int ncol,
                                          int col, int k0) {
  bf16x8 r;
#pragma unroll
  for (int j = 0; j < 8; ++j) r[j] = (__bf16)W[(k0 + j) * ncol + col];
  return r;
}

#define MFMA(A, B, C) __builtin_amdgcn_mfma_f32_16x16x32_bf16((A), (B), (C), 0, 0, 0)

__global__ __launch_bounds__(256, 1)
void kvmr_kernel(const float* __restrict__ inputs,   // [2048][512][64]
                 const float* __restrict__ w_ih,     // [96][66]
                 const float* __restrict__ w_hh,     // [96][32]
                 const float* __restrict__ b_ih,     // [96]
                 const float* __restrict__ b_hh,     // [96]
                 const float* __restrict__ W_key,    // [64][32]
                 const float* __restrict__ b_key,    // [64]
                 const float* __restrict__ W_query,  // [64][32]
                 const float* __restrict__ b_query,  // [64]
                 const float* __restrict__ W_value,  // [64][32]
                 const float* __restrict__ b_value,  // [64]
                 const float* __restrict__ W_recall, // [2][64]
                 const float* __restrict__ b_recall, // [2]
                 const float* __restrict__ W_out,    // [16][32]
                 const float* __restrict__ b_out,    // [16]
                 float* __restrict__ out_all) {      // outputs | hiddens
  const int tid = threadIdx.x;
  const int l  = tid & 63;
  const int c  = l & 15;
  const int q4 = l >> 4;
  const int w  = tid >> 6;
  const int b0 = blockIdx.x * 16;

  __shared__ __align__(16) uint32_t h_pk[4][16 * 16];      // per-wave prologue relay (packed)
  __shared__ __align__(16) __bf16 kv_pro[4][3][16 * 64];   // per-wave fold relay

  // ---- weights as register-resident B-fragments ----
  bf16x8 Bih[6][2];       // standard order (A = x from global, standard k)
  bf16x8 BhhS[6];         // sigma order (A = h via bpermute/packed relay)
#pragma unroll
  for (int g = 0; g < 6; ++g) {
#pragma unroll
    for (int kc = 0; kc < 2; ++kc)
      Bih[g][kc] = ldfrag(w_ih, 66, 16 * g + c, 32 * kc + 8 * q4);
    BhhS[g] = ldfragS(w_hh, 16 * g + c, q4);
  }
  bf16x8 BqS[4], BkS[4], BvS[4];
#pragma unroll
  for (int g = 0; g < 4; ++g) {
    BqS[g] = ldfragS(W_query, 16 * g + c, q4);
    BkS[g] = ldfragS(W_key,   16 * g + c, q4);
    BvS[g] = ldfragS(W_value, 16 * g + c, q4);
  }
  bf16x8 BoS = ldfragS(W_out, c, q4);

  float wih64[6], wih65[6];
#pragma unroll
  for (int g = 0; g < 6; ++g) {
    wih64[g] = w_ih[(16 * g + c) * 66 + 64];
    wih65[g] = w_ih[(16 * g + c) * 66 + 65];
  }
  float wr0f[4], wr1f[4];
#pragma unroll
  for (int g = 0; g < 4; ++g) {
    wr0f[g] = W_recall[16 * g + c];
    wr1f[g] = W_recall[64 + 16 * g + c];
  }

  float bias_rz[4], bias_xn[2], bias_hn[2];
#pragma unroll
  for (int g = 0; g < 4; ++g) bias_rz[g] = b_ih[16 * g + c] + b_hh[16 * g + c];
#pragma unroll
  for (int gg = 0; gg < 2; ++gg) {
    bias_xn[gg] = b_ih[64 + 16 * gg + c];
    bias_hn[gg] = b_hh[64 + 16 * gg + c];
  }
  float bq4[4], bk4[4], bv4[4];
#pragma unroll
  for (int g = 0; g < 4; ++g) {
    bq4[g] = b_query[16 * g + c];
    bk4[g] = b_key[16 * g + c];
    bv4[g] = b_value[16 * g + c];
  }
  float bo1 = b_out[c];
  float br0 = b_recall[0], br1 = b_recall[1];

  float* outW = out_all + (size_t)(b0 + 4 * q4 + w) * SL * NO + c;
  float* hidW = out_all + (size_t)NB * SL * NO + (size_t)(b0 + 4 * q4 + w) * SL * NH + c;

  // ---- prologue state ----
  f32x4 hD0 = splat4(0.0f), hD1 = splat4(0.0f);
  f32x4 keysR[3][4], valsR[3][4];
#pragma unroll
  for (int s = 0; s < 3; ++s)
#pragma unroll
    for (int g = 0; g < 4; ++g) { keysR[s][g] = splat4(0.0f); valsR[s][g] = splat4(0.0f); }

  f32x4 hPartRZ[4], hPartHN[2];
#pragma unroll
  for (int g = 0; g < 4; ++g) hPartRZ[g] = splat4(bias_rz[g]);
#pragma unroll
  for (int gg = 0; gg < 2; ++gg) hPartHN[gg] = splat4(bias_hn[gg]);
  float retr0c[4] = {0.f, 0.f, 0.f, 0.f};
  float retr1c[4] = {0.f, 0.f, 0.f, 0.f};

  // ---- prologue x double prefetch (rows b0+c; all 16 rows genuine) ----
  const float* xp = inputs + (size_t)(b0 + c) * (SL * NIN) + 8 * q4;
  f32x4 xb[2][4];
#pragma unroll
  for (int p = 0; p < 2; ++p) {
    const float* xq = xp + p * NIN;
    xb[p][0] = *(const f32x4*)(xq + 0);
    xb[p][1] = *(const f32x4*)(xq + 4);
    xb[p][2] = *(const f32x4*)(xq + 32);
    xb[p][3] = *(const f32x4*)(xq + 36);
  }

  // =========================================================================
  // Prologue: t = 0,1,2 — redundant per wave, private LDS, no sync.
  // =========================================================================
#pragma unroll
  for (int t = 0; t < 3; ++t) {
    const int pb = t & 1;
    bf16x8 ax0, ax1;
#pragma unroll
    for (int j = 0; j < 4; ++j) {
      ax0[j]     = (__bf16)xb[pb][0][j];
      ax0[4 + j] = (__bf16)xb[pb][1][j];
      ax1[j]     = (__bf16)xb[pb][2][j];
      ax1[4 + j] = (__bf16)xb[pb][3][j];
    }
    {
      const float* xq = xp + (t + 2) * NIN;
      xb[pb][0] = *(const f32x4*)(xq + 0);
      xb[pb][1] = *(const f32x4*)(xq + 4);
      xb[pb][2] = *(const f32x4*)(xq + 32);
      xb[pb][3] = *(const f32x4*)(xq + 36);
    }

    f32x4 accRZ[4], accXN[2];
#pragma unroll
    for (int g = 0; g < 4; ++g) {
      f32x4 a = hPartRZ[g];
#pragma unroll
      for (int r = 0; r < 4; ++r) a[r] += retr0c[r] * wih64[g] + retr1c[r] * wih65[g];
      a = MFMA(ax0, Bih[g][0], a);
      a = MFMA(ax1, Bih[g][1], a);
      accRZ[g] = a;
    }
#pragma unroll
    for (int gg = 0; gg < 2; ++gg) {
      f32x4 a = splat4(bias_xn[gg]);
#pragma unroll
      for (int r = 0; r < 4; ++r) a[r] += retr0c[r] * wih64[4 + gg] + retr1c[r] * wih65[4 + gg];
      a = MFMA(ax0, Bih[4 + gg][0], a);
      a = MFMA(ax1, Bih[4 + gg][1], a);
      accXN[gg] = a;
    }

    f32x4 hn0, hn1;
#pragma unroll
    for (int r = 0; r < 4; ++r) {
      float rg0 = sigmoidf_(accRZ[0][r]);
      float zg0 = sigmoidf_(accRZ[2][r]);
      float ng0 = tanhf_(accXN[0][r] + rg0 * hPartHN[0][r]);
      hn0[r] = (1.0f - zg0) * ng0 + zg0 * hD0[r];
      float rg1 = sigmoidf_(accRZ[1][r]);
      float zg1 = sigmoidf_(accRZ[3][r]);
      float ng1 = tanhf_(accXN[1][r] + rg1 * hPartHN[1][r]);
      hn1[r] = (1.0f - zg1) * ng1 + zg1 * hD1[r];
    }
    hD0 = hn0; hD1 = hn1;

    hidW[t * NH]      = pick4v(hn0, w);
    hidW[t * NH + 16] = pick4v(hn1, w);
    // packed sigma relay: write pair u32, read b128 of 4 consecutive pairs
#pragma unroll
    for (int r = 0; r < 4; ++r)
      h_pk[w][(4 * q4 + r) * 16 + c] = cvtpk_(hn0[r], hn1[r]);
    bf16x8 hA = *(const bf16x8*)&h_pk[w][c * 16 + 4 * q4];

#pragma unroll
    for (int g = 0; g < 4; ++g) hPartRZ[g] = MFMA(hA, BhhS[g], splat4(bias_rz[g]));
#pragma unroll
    for (int gg = 0; gg < 2; ++gg) hPartHN[gg] = MFMA(hA, BhhS[4 + gg], splat4(bias_hn[gg]));
    f32x4 oT = MFMA(hA, BoS, splat4(bo1));
    outW[t * NO] = pick4v(oT, w);

    f32x4 qT[4], kT[4], vT[4];
#pragma unroll
    for (int g = 0; g < 4; ++g) {
      qT[g] = MFMA(hA, BqS[g], splat4(bq4[g]));
      kT[g] = MFMA(hA, BkS[g], splat4(bk4[g]));
      vT[g] = MFMA(hA, BvS[g], splat4(bv4[g]));
    }

    // attention over slots < t (scores on pre-write memory)
#pragma unroll
    for (int r = 0; r < 4; ++r) {
      float d0 = qT[0][r] * keysR[0][0][r] + qT[1][r] * keysR[0][1][r] +
                 qT[2][r] * keysR[0][2][r] + qT[3][r] * keysR[0][3][r];
      float d1 = qT[0][r] * keysR[1][0][r] + qT[1][r] * keysR[1][1][r] +
                 qT[2][r] * keysR[1][2][r] + qT[3][r] * keysR[1][3][r];
      float s0 = (t > 0) ? rowsum16(d0) : -1e30f;
      float s1 = (t > 1) ? rowsum16(d1) : -1e30f;
      float s2 = -1e30f;
      float mx = fmaxf(s0, fmaxf(s1, s2));
      float e0 = __expf(s0 - mx), e1 = __expf(s1 - mx), e2 = __expf(s2 - mx);
      float inv = rcpf_(e0 + e1 + e2);
      float u0 = 0.f, u1 = 0.f;
#pragma unroll
      for (int g = 0; g < 4; ++g) {
        float rd = (e0 * valsR[0][g][r] + e1 * valsR[1][g][r] + e2 * valsR[2][g][r]) * inv;
        u0 += rd * wr0f[g];
        u1 += rd * wr1f[g];
      }
      u0 = rowsum16(u0);
      u1 = rowsum16(u1);
      retr0c[r] = (t > 0) ? (u0 + br0) : 0.0f;
      retr1c[r] = (t > 0) ? (u1 + br1) : 0.0f;
    }

#pragma unroll
    for (int g = 0; g < 4; ++g) { keysR[t][g] = kT[g]; valsR[t][g] = vT[g]; }
  }

  // =========================================================================
  // Fold (memory frozen after t=2): M = keys@Wq, Cq = bq.keys, VR = vals.Wr^T
  // =========================================================================
#pragma unroll
  for (int s = 0; s < 3; ++s)
#pragma unroll
    for (int g = 0; g < 4; ++g)
#pragma unroll
      for (int r = 0; r < 4; ++r)
        kv_pro[w][s][(4 * q4 + r) * 64 + 16 * g + c] = (__bf16)keysR[s][g][r];

  bf16x8 Bwq[2][2];
#pragma unroll
  for (int ch = 0; ch < 2; ++ch)
#pragma unroll
    for (int ct = 0; ct < 2; ++ct)
      Bwq[ch][ct] = ldfragT(W_query, 32, 16 * ct + c, 32 * ch + 8 * q4);

  float M0c[3][4], M1c[3][4], Cq[3][4], VRa[3][4], VRb[3][4];
#pragma unroll
  for (int s = 0; s < 3; ++s) {
    const bf16x8 ak0 = *(const bf16x8*)&kv_pro[w][s][c * 64 + 8 * q4];
    const bf16x8 ak1 = *(const bf16x8*)&kv_pro[w][s][c * 64 + 32 + 8 * q4];
    f32x4 m0 = MFMA(ak1, Bwq[1][0], MFMA(ak0, Bwq[0][0], splat4(0.0f)));
    f32x4 m1 = MFMA(ak1, Bwq[1][1], MFMA(ak0, Bwq[0][1], splat4(0.0f)));
#pragma unroll
    for (int r = 0; r < 4; ++r) {
      M0c[s][r] = m0[r];
      M1c[s][r] = m1[r];
      Cq[s][r] = rowsum16(keysR[s][0][r] * bq4[0] + keysR[s][1][r] * bq4[1] +
                          keysR[s][2][r] * bq4[2] + keysR[s][3][r] * bq4[3]);
      VRa[s][r] = rowsum16(valsR[s][0][r] * wr0f[0] + valsR[s][1][r] * wr0f[1] +
                           valsR[s][2][r] * wr0f[2] + valsR[s][3][r] * wr0f[3]);
      VRb[s][r] = rowsum16(valsR[s][0][r] * wr1f[0] + valsR[s][1][r] * wr1f[1] +
                           valsR[s][2][r] * wr1f[2] + valsR[s][3][r] * wr1f[3]);
    }
  }

  float M0w[3], M1w[3], Cqw[3], VAw[3], VBw[3];
#pragma unroll
  for (int s = 0; s < 3; ++s) {
    M0w[s] = pick4f(M0c[s][0], M0c[s][1], M0c[s][2], M0c[s][3], w);
    M1w[s] = pick4f(M1c[s][0], M1c[s][1], M1c[s][2], M1c[s][3], w);
    Cqw[s] = pick4f(Cq[s][0],  Cq[s][1],  Cq[s][2],  Cq[s][3],  w);
    VAw[s] = pick4f(VRa[s][0], VRa[s][1], VRa[s][2], VRa[s][3], w);
    VBw[s] = pick4f(VRb[s][0], VRb[s][1], VRb[s][2], VRb[s][3], w);
  }

  // ---- t = 3 closed form (h_3 flushed to 0) ----
  hidW[3 * NH]      = 0.0f;
  hidW[3 * NH + 16] = 0.0f;
  outW[3 * NO]      = bo1;

  float retr0, retr1;
  {
    float s0 = Cqw[0], s1 = Cqw[1], s2 = Cqw[2];
    float mx = fmaxf(s0, fmaxf(s1, s2));
    float e0 = __expf(s0 - mx), e1 = __expf(s1 - mx), e2 = __expf(s2 - mx);
    float inv = rcpf_(e0 + e1 + e2);
    retr0 = br0 + (e0 * VAw[0] + e1 * VAw[1] + e2 * VAw[2]) * inv;
    retr1 = br1 + (e0 * VBw[0] + e1 * VBw[1] + e2 * VBw[2]) * inv;
  }

  // raw hh-parts (bias_rz lives in xa path; bias_hn in bhnQ C-quad)
  float hprz0 = 0.0f, hprz1 = 0.0f, hprz2 = 0.0f, hprz3 = 0.0f;
  float hphn0 = bias_hn[0], hphn1 = bias_hn[1];
  float h0p = 0.0f, h1p = 0.0f;

  // ---- persistent MFMA C-quads (loop-invariant; zero per-step mov cost) ----
  const f32x4 Zq = splat4(0.0f);
  f32x4 biasQ[6];
#pragma unroll
  for (int g = 0; g < 4; ++g) biasQ[g] = splat4(bias_rz[g]);
  biasQ[4] = splat4(bias_xn[0]);
  biasQ[5] = splat4(bias_xn[1]);
  const f32x4 bhnQ0 = splat4(bias_hn[0]);
  const f32x4 bhnQ1 = splat4(bias_hn[1]);
  const f32x4 boQ   = splat4(bo1);

  // bpermute source-lane byte indices: dst lane l pulls from 16*((l>>2)&3)+4*(l>>4)+i
  const int bp0 = 4 * (16 * ((l >> 2) & 3) + 4 * (l >> 4));
  const int bp1 = bp0 + 4;
  const int bp2 = bp0 + 8;
  const int bp3 = bp0 + 12;

  // ---- steady x pipeline: lane (q4,c) loads x[row b0+4*(c>>2)+w][step T+(c&3)]
  //      -> A row c = x_{T+(c&3)}[row 4*(c>>2)+w]; D comp r = step T+r, own row.
  const float* xgp = inputs + (size_t)(b0 + 4 * (c >> 2) + w) * (SL * NIN) +
                     (size_t)(c & 3) * NIN + 8 * q4;
  f32x4 xg[4];
#define LOADXG(T) {                                                           \
    const float* q_ = xgp + (size_t)(T) * NIN;                                \
    xg[0] = *(const f32x4*)(q_ + 0);                                          \
    xg[1] = *(const f32x4*)(q_ + 4);                                          \
    xg[2] = *(const f32x4*)(q_ + 32);                                         \
    xg[3] = *(const f32x4*)(q_ + 36);                                         \
  }
#define XACOMP(DST) {                                                         \
    bf16x8 ax0, ax1;                                                          \
    _Pragma("unroll") for (int j = 0; j < 4; ++j) {                           \
      ax0[j]     = (__bf16)xg[0][j];                                          \
      ax0[4 + j] = (__bf16)xg[1][j];                                          \
      ax1[j]     = (__bf16)xg[2][j];                                          \
      ax1[4 + j] = (__bf16)xg[3][j];                                          \
    }                                                                         \
    _Pragma("unroll") for (int g = 0; g < 6; ++g)                             \
      DST[g] = MFMA(ax1, Bih[g][1], MFMA(ax0, Bih[g][0], biasQ[g]));          \
  }

  f32x4 xaA[6], xaB[6];
  LOADXG(4)
  XACOMP(xaA)        // xa for steps 4..7 (comp r = step 4+r), biases included
  LOADXG(8)          // x for steps 8..11 (consumed by first group's XACOMP)

  float sbh0[16], sbh1[16], sbo[16];

  // ---- one step: XC = current xa array, R = comp literal, U = store slot ----
#define STEP(XC, R, U) {                                                      \
    float pr0 = XC[0][R] + hprz0 + retr0 * wih64[0] + retr1 * wih65[0];       \
    float pr1 = XC[1][R] + hprz1 + retr0 * wih64[1] + retr1 * wih65[1];       \
    float pz0 = XC[2][R] + hprz2 + retr0 * wih64[2] + retr1 * wih65[2];       \
    float pz1 = XC[3][R] + hprz3 + retr0 * wih64[3] + retr1 * wih65[3];       \
    float pn0 = XC[4][R] + retr0 * wih64[4] + retr1 * wih65[4];               \
    float pn1 = XC[5][R] + retr0 * wih64[5] + retr1 * wih65[5];               \
    float rg0 = sigmoidf_(pr0), rg1 = sigmoidf_(pr1);                         \
    float zg0 = sigmoidf_(pz0), zg1 = sigmoidf_(pz1);                         \
    float ng0 = tanhf_(pn0 + rg0 * hphn0);                                    \
    float ng1 = tanhf_(pn1 + rg1 * hphn1);                                    \
    float h0 = (1.0f - zg0) * ng0 + zg0 * h0p;                                \
    float h1 = (1.0f - zg1) * ng1 + zg1 * h1p;                                \
    h0p = h0; h1p = h1;                                                       \
    sbh0[U] = h0; sbh1[U] = h1;                                               \
    uint32_t hpk = cvtpk_(h0, h1);                                            \
    uint32_t f0 = (uint32_t)__builtin_amdgcn_ds_bpermute(bp0, (int)hpk);      \
    uint32_t f1 = (uint32_t)__builtin_amdgcn_ds_bpermute(bp1, (int)hpk);      \
    uint32_t f2 = (uint32_t)__builtin_amdgcn_ds_bpermute(bp2, (int)hpk);      \
    uint32_t f3 = (uint32_t)__builtin_amdgcn_ds_bpermute(bp3, (int)hpk);      \
    bf16x8 hA = frag4(f0, f1, f2, f3);                                        \
    { f32x4 d_;                                                               \
      d_ = MFMA(hA, BhhS[0], Zq);    hprz0 = d_[0];                           \
      d_ = MFMA(hA, BhhS[1], Zq);    hprz1 = d_[0];                           \
      d_ = MFMA(hA, BhhS[2], Zq);    hprz2 = d_[0];                           \
      d_ = MFMA(hA, BhhS[3], Zq);    hprz3 = d_[0];                           \
      d_ = MFMA(hA, BhhS[4], bhnQ0); hphn0 = d_[0];                           \
      d_ = MFMA(hA, BhhS[5], bhnQ1); hphn1 = d_[0];                           \
      d_ = MFMA(hA, BoS,     boQ);   sbo[U] = d_[0];                          \
    }                                                                         \
    float p0 = h0 * M0w[0] + h1 * M1w[0];                                     \
    float p1 = h0 * M0w[1] + h1 * M1w[1];                                     \
    float p2 = h0 * M0w[2] + h1 * M1w[2];                                     \
    p0 = rowsum16(p0) + Cqw[0];                                               \
    p1 = rowsum16(p1) + Cqw[1];                                               \
    p2 = rowsum16(p2) + Cqw[2];                                               \
    float mx = fmaxf(p0, fmaxf(p1, p2));                                      \
    float e0 = __expf(p0 - mx), e1 = __expf(p1 - mx), e2 = __expf(p2 - mx);   \
    float inv = rcpf_(e0 + e1 + e2);                                          \
    retr0 = br0 + (e0 * VAw[0] + e1 * VAw[1] + e2 * VAw[2]) * inv;            \
    retr1 = br1 + (e0 * VBw[0] + e1 * VBw[1] + e2 * VBw[2]) * inv;            \
  }

  // ---- group of 4 steps: compute next-group xa, refill xg, run 4 STEPs ----
  // XC consumed (steps TT..TT+3); XN produced (steps TT+4..TT+7).
#define GROUP4(TT, XC, XN, U0, DONEXT, DOPF) {                                \
    if (DONEXT) { XACOMP(XN) }                                                \
    if (DOPF)   { LOADXG((TT) + 8) }                                          \
    STEP(XC, 0, (U0) + 0)                                                     \
    STEP(XC, 1, (U0) + 1)                                                     \
    STEP(XC, 2, (U0) + 2)                                                     \
    STEP(XC, 3, (U0) + 3)                                                     \
  }

#define FLUSH(TB, N)                                                          \
    _Pragma("unroll") for (int r = 0; r < (N); ++r) {                         \
      hidW[((TB) + r) * NH]      = sbh0[r];                                   \
      hidW[((TB) + r) * NH + 16] = sbh1[r];                                   \
      outW[((TB) + r) * NO]      = sbo[r];                                    \
    }

  // =========================================================================
  // Steady state t = 4..511: 31 superblocks of 16 + tail of 12.
  // =========================================================================
  for (int tb = 4; tb < 500; tb += 16) {
    GROUP4(tb + 0,  xaA, xaB, 0,  1, 1)
    GROUP4(tb + 4,  xaB, xaA, 4,  1, 1)
    GROUP4(tb + 8,  xaA, xaB, 8,  1, 1)
    GROUP4(tb + 12, xaB, xaA, 12, 1, 1)
    FLUSH(tb, 16)
  }
  {
    GROUP4(500, xaA, xaB, 0, 1, 1)   // refill loads x508..x511 (valid)
    GROUP4(504, xaB, xaA, 4, 1, 0)   // XN = xa(508..511) from xg; no refill
    GROUP4(508, xaA, xaB, 8, 0, 0)   // consume xa(508..511); nothing ahead
    FLUSH(500, 12)
  }
#undef STEP
#undef GROUP4
#undef FLUSH
#undef LOADXG
#undef XACOMP
}

extern "C" void kernel_launch(void* const* d_in, const int* in_sizes, int n_in,
                              void* d_out, int out_size, void* d_ws, size_t ws_size,
                              hipStream_t stream) {
  (void)in_sizes; (void)n_in; (void)out_size; (void)d_ws; (void)ws_size;
  const float* inputs   = (const float*)d_in[0];
  const float* w_ih     = (const float*)d_in[1];
  const float* w_hh     = (const float*)d_in[2];
  const float* b_ih     = (const float*)d_in[3];
  const float* b_hh     = (const float*)d_in[4];
  const float* W_key    = (const float*)d_in[5];
  const float* b_key    = (const float*)d_in[6];
  const float* W_query  = (const float*)d_in[7];
  const float* b_query  = (const float*)d_in[8];
  const float* W_value  = (const float*)d_in[9];
  const float* b_value  = (const float*)d_in[10];
  const float* W_recall = (const float*)d_in[11];
  const float* b_recall = (const float*)d_in[12];
  const float* W_out    = (const float*)d_in[13];
  const float* b_out    = (const float*)d_in[14];
  float* out = (float*)d_out;

  kvmr_kernel<<<dim3(128), dim3(256), 0, stream>>>(
      inputs, w_ih, w_hh, b_ih, b_hh, W_key, b_key, W_query, b_query,
      W_value, b_value, W_recall, b_recall, W_out, b_out, out);
}